// Round 8
// baseline (393.463 us; speedup 1.0000x reference)
//
#include <hip/hip_runtime.h>

// B=4, L=64, C=64, H=W=32, K=3, CONN=4
#define NIMG 256
#define CCH 64
#define HWSZ 1024
#define IMG_NHWC 65536            // 1024 px * 64 c (bf16 elements per image)

typedef __attribute__((ext_vector_type(8))) short  s16x8;
typedef __attribute__((ext_vector_type(4))) short  s16x4;
typedef __attribute__((ext_vector_type(4))) float  f32x4;

__device__ __forceinline__ unsigned short f2bf(float f) {
    unsigned u = __builtin_bit_cast(unsigned, f);
    u += 0x7fffu + ((u >> 16) & 1u);          // RNE
    return (unsigned short)(u >> 16);
}
__device__ __forceinline__ float bf2f(unsigned short h) {
    unsigned u = ((unsigned)h) << 16;
    return __builtin_bit_cast(float, u);
}

// async global->LDS, 16B per lane. LDS dest = wave-uniform base + lane*16 (m104).
__device__ __forceinline__ void gload_lds16(const void* g, void* l) {
    __builtin_amdgcn_global_load_lds(
        (const __attribute__((address_space(1))) unsigned int*)g,
        (__attribute__((address_space(3))) unsigned int*)l, 16, 0, 0);
}

// ---------------------------------------------------------------------------
// nbr[n][4] + per-row valid-neighbor count from adjacency mask
// (byte-bool or int32, auto-detected). Validated R2.
// ---------------------------------------------------------------------------
__global__ __launch_bounds__(256) void build_nbr_kernel(const unsigned char* __restrict__ mraw,
                                                        int* __restrict__ nbr,
                                                        int* __restrict__ cnt) {
    __shared__ int nz;
    int t = threadIdx.x;
    if (t == 0) nz = 0;
    __syncthreads();
    int local = 0;
    for (int i = t; i < 16384; i += 256) local += (mraw[i] != 0) ? 1 : 0;
    atomicAdd(&nz, local);
    __syncthreads();
    bool isByte = (nz == 1024);
    const int* mi = (const int*)mraw;
    int c = 0;
    int base = t * 64;
    for (int j = 0; j < 64; ++j) {
        int v = isByte ? (int)mraw[base + j] : mi[base + j];
        if (v != 0 && c < 4) { nbr[t * 4 + c] = j; ++c; }
    }
    cnt[t] = c;
    for (; c < 4; ++c) nbr[t * 4 + c] = -1;
}

// ---------------------------------------------------------------------------
// Pack conv weights OIHW f32 -> [conv][tap][co][ci] bf16 (r4 layout, A-loads
// read 16B (lm,kg,g)-fragments straight from L2).
// ---------------------------------------------------------------------------
__global__ __launch_bounds__(256) void pack_w_kernel(const float* __restrict__ w0,
                                                     const float* __restrict__ w1,
                                                     const float* __restrict__ w2,
                                                     const float* __restrict__ w3,
                                                     unsigned short* __restrict__ wp) {
    int idx = blockIdx.x * 256 + threadIdx.x;      // 4*9*64*64 = 147456
    if (idx >= 147456) return;
    int ci = idx & 63, co = (idx >> 6) & 63;
    int tc = idx >> 12;                            // conv*9 + tap
    int cv = tc / 9, tap = tc - cv * 9;
    const float* w = (cv == 0) ? w0 : (cv == 1) ? w1 : (cv == 2) ? w2 : w3;
    wp[idx] = f2bf(w[(co * 64 + ci) * 9 + tap]);
}

// ---------------------------------------------------------------------------
// NCHW f32 -> NHWC bf16, LDS-tiled transpose. Block = quarter image (256 px).
// ---------------------------------------------------------------------------
__global__ __launch_bounds__(256) void to_nhwc_kernel(const float* __restrict__ x,
                                                      unsigned short* __restrict__ xb) {
    __shared__ unsigned short lds[256 * 68];
    int bid = blockIdx.x;                 // 1024
    int n = bid >> 2, px0 = (bid & 3) * 256;
    int t = threadIdx.x, w = t >> 6, l = t & 63;

    #pragma unroll
    for (int pp = 0; pp < 8; ++pp) {      // channel pairs per wave
        int c = w * 16 + pp * 2;
        const float* s0 = x + ((size_t)(n * 64 + c)) * HWSZ + px0;
        const float* s1 = s0 + HWSZ;
        #pragma unroll
        for (int ch = 0; ch < 4; ++ch) {
            int px = ch * 64 + l;
            unsigned pack = (unsigned)f2bf(s0[px]) | ((unsigned)f2bf(s1[px]) << 16);
            *(unsigned*)((char*)lds + px * 136 + c * 2) = pack;
        }
    }
    __syncthreads();
    #pragma unroll
    for (int it = 0; it < 8; ++it) {
        int pos = it * 256 + t;
        int px = pos >> 3, c0 = (pos & 7) * 8;
        const char* src = (const char*)lds + px * 136 + c0 * 2;
        s16x4 v0 = *(const s16x4*)src;
        s16x4 v1 = *(const s16x4*)(src + 8);
        unsigned short* dst = xb + ((size_t)(n * 1024) + px0 + px) * 64 + c0;
        *(s16x4*)dst = v0;
        *(s16x4*)(dst + 4) = v1;
    }
}

// ---------------------------------------------------------------------------
// xa[n] = sum_k src[nbr[n][k]]  (NHWC bf16 -> NHWC bf16, f32 accumulate).
// Linearity of conv: conv(sum x_j) = sum conv(x_j); bias handled via cnt.
// ---------------------------------------------------------------------------
__global__ __launch_bounds__(256) void agg_kernel(const unsigned short* __restrict__ src,
                                                  unsigned short* __restrict__ dst,
                                                  const int* __restrict__ nbr) {
    int bid = blockIdx.x;                          // 8192
    int n = bid >> 5;                              // uniform per block
    int b = n >> 6;
    int rem = ((bid & 31) << 8) + threadIdx.x;     // 16B unit within image
    float s[8] = {0.f, 0.f, 0.f, 0.f, 0.f, 0.f, 0.f, 0.f};
    #pragma unroll
    for (int k = 0; k < 4; ++k) {
        int jn = nbr[n * 4 + k];
        if (jn >= 0) {
            s16x8 nv = *(const s16x8*)(src + ((((size_t)(b * 64 + jn)) << 13) + rem) * 8);
            #pragma unroll
            for (int j = 0; j < 8; ++j) s[j] += bf2f((unsigned short)nv[j]);
        }
    }
    s16x8 o;
    #pragma unroll
    for (int j = 0; j < 8; ++j) o[j] = (short)f2bf(s[j]);
    *(s16x8*)(dst + ((((size_t)n) << 13) + rem) * 8) = o;
}

// ---------------------------------------------------------------------------
// FUSED conv layer via input aggregation:
//   acc = conv_wX(actX) + conv_wN(actA);   (single accumulator, 18 taps)
//   MODE 0: out = relu(acc + bX + cnt*bN)           -> NHWC bf16
//   MODE 1: out = relu(acc + bX + cnt*bN + resid)   -> NCHW f32 (final output)
// Block = image x 8-row stripe x all 64 co; wave = 2 rows; acc 4m x 4p.
// LDS: two tiles [10 rows][32 cols][64 ci] bf16 = 2 x 40 KiB = 80 KiB exactly
// -> 2 blocks/CU. No halo columns stored: edge lanes predicated to zero
// (compile-time per dx). Staging: global_load_lds w16, pre-swizzled source +
// linear dest; reads use ^((col&7)<<4) (r4/r7-proven, 0 conflicts).
// A-frags (weights) from global/L2 (r4-proven) - keeps the LDS pipe for B.
// ---------------------------------------------------------------------------
template<int MODE>
__global__ __launch_bounds__(256, 2) void conv_fused_kernel(const unsigned short* __restrict__ actX,
                                                            const unsigned short* __restrict__ actA,
                                                            const unsigned short* __restrict__ wX,
                                                            const unsigned short* __restrict__ wN,
                                                            const float* __restrict__ bX,
                                                            const float* __restrict__ bN,
                                                            const int* __restrict__ cnt,
                                                            const float* __restrict__ resid,
                                                            void* __restrict__ outp) {
    __shared__ unsigned short ldsX[10 * 32 * 64];  // 40960 B
    __shared__ unsigned short ldsA[10 * 32 * 64];  // 40960 B
    int bid = blockIdx.x;                          // 1024
    int n = bid >> 2, stripe = bid & 3;
    int y0 = stripe * 8;
    int t = threadIdx.x, w = t >> 6, l = t & 63;

    // ---- stage both input stripes (+row halo; no col halo) ----
    {
        const unsigned short* imgX = actX + ((size_t)n << 16);
        const unsigned short* imgA = actA + ((size_t)n << 16);
        int x1 = (t >> 3) & 31, slot = t & 7;
        int sslot = slot ^ (x1 & 7);               // pre-swizzled global source
        // linear LDS dest: offset w*1024 + l*16 == t*16 within each row
        #pragma unroll
        for (int r = 0; r < 10; ++r) {
            int y = y0 - 1 + r;
            if (y >= 0 && y < 32) {                // block-uniform branch
                int gsrc = (y * 32 + x1) * 64 + sslot * 8;
                gload_lds16(imgX + gsrc, (char*)ldsX + r * 4096 + w * 1024);
                gload_lds16(imgA + gsrc, (char*)ldsA + r * 4096 + w * 1024);
            } else {
                s16x8 z = {0,0,0,0,0,0,0,0};
                *(s16x8*)((char*)ldsX + r * 4096 + t * 16) = z;
                *(s16x8*)((char*)ldsA + r * 4096 + t * 16) = z;
            }
        }
    }
    __syncthreads();

    int lm = l & 15, kg = l >> 4;
    f32x4 acc[4][4];
    #pragma unroll
    for (int m = 0; m < 4; ++m)
        #pragma unroll
        for (int p = 0; p < 4; ++p) acc[m][p] = (f32x4){0.f, 0.f, 0.f, 0.f};

    #pragma unroll
    for (int tt = 0; tt < 18; ++tt) {
        const int tap = (tt < 9) ? tt : tt - 9;
        const int dy = tap / 3, dx = tap % 3;
        const unsigned short* wlane = ((tt < 9) ? wX : wN) + lm * 64 + kg * 8;
        const char* tile = (tt < 9) ? (const char*)ldsX : (const char*)ldsA;
        #pragma unroll
        for (int g = 0; g < 2; ++g) {
            s16x8 a[4], bfr[4];
            #pragma unroll
            for (int m = 0; m < 4; ++m)
                a[m] = *(const s16x8*)(wlane + (tap * 64 + m * 16) * 64 + g * 32);
            #pragma unroll
            for (int p = 0; p < 4; ++p) {
                int r   = 2 * w + (p >> 1) + dy;               // 0..9
                int col = (p & 1) * 16 + lm + dx - 1;          // -1..32
                if (dx == 1) {
                    int lb = (r * 4096 + col * 128 + (g * 4 + kg) * 16) ^ ((col & 7) << 4);
                    bfr[p] = *(const s16x8*)(tile + lb);
                } else {
                    bool ok = (unsigned)col < 32u;
                    int cc = ok ? col : 0;
                    int lb = (r * 4096 + cc * 128 + (g * 4 + kg) * 16) ^ ((cc & 7) << 4);
                    s16x8 v = *(const s16x8*)(tile + lb);
                    s16x8 z = {0,0,0,0,0,0,0,0};
                    bfr[p] = ok ? v : z;
                }
            }
            #pragma unroll
            for (int m = 0; m < 4; ++m)
                #pragma unroll
                for (int p = 0; p < 4; ++p)
                    acc[m][p] = __builtin_amdgcn_mfma_f32_16x16x32_bf16(a[m], bfr[p], acc[m][p], 0, 0, 0);
        }
    }

    // ---- epilogue. D: col(px)=lane&15, row(co)=kg*4+reg (m89) ----
    float cf = (float)cnt[n];
    #pragma unroll
    for (int m = 0; m < 4; ++m) {
        f32x4 bxv = *(const f32x4*)(bX + m * 16 + kg * 4);
        f32x4 bnv = *(const f32x4*)(bN + m * 16 + kg * 4);
        #pragma unroll
        for (int p = 0; p < 4; ++p) {
            int y  = y0 + 2 * w + (p >> 1);
            int xx = (p & 1) * 16 + lm;
            if (MODE == 0) {
                s16x4 o;
                #pragma unroll
                for (int j = 0; j < 4; ++j) {
                    float v = acc[m][p][j] + bxv[j] + cf * bnv[j];
                    o[j] = (short)f2bf(fmaxf(v, 0.f));
                }
                *(s16x4*)((unsigned short*)outp +
                          (((size_t)n * 1024 + y * 32 + xx) * 64) + m * 16 + kg * 4) = o;
            } else {
                float* of = (float*)outp;
                #pragma unroll
                for (int j = 0; j < 4; ++j) {
                    int co = m * 16 + kg * 4 + j;
                    size_t ad = ((size_t)(n * 64 + co)) * 1024 + y * 32 + xx;
                    float v = acc[m][p][j] + bxv[j] + cf * bnv[j] + resid[ad];
                    of[ad] = fmaxf(v, 0.f);
                }
            }
        }
    }
}

// ---------------------------------------------------------------------------
extern "C" void kernel_launch(void* const* d_in, const int* in_sizes, int n_in,
                              void* d_out, int out_size, void* d_ws, size_t ws_size,
                              hipStream_t stream) {
    const float* x    = (const float*)d_in[0];
    const float* w_x0 = (const float*)d_in[1];
    const float* b_x0 = (const float*)d_in[2];
    const float* w_n0 = (const float*)d_in[3];
    const float* b_n0 = (const float*)d_in[4];
    const float* w_x1 = (const float*)d_in[5];
    const float* b_x1 = (const float*)d_in[6];
    const float* w_n1 = (const float*)d_in[7];
    const float* b_n1 = (const float*)d_in[8];
    const unsigned char* mask = (const unsigned char*)d_in[9];

    unsigned short* xb    = (unsigned short*)d_ws;              // x NHWC bf16
    unsigned short* xa    = xb + (size_t)NIMG * IMG_NHWC;       // aggregated input (xa, later ha)
    unsigned short* hb    = xa + (size_t)NIMG * IMG_NHWC;       // h NHWC bf16
    unsigned short* wpack = hb + (size_t)NIMG * IMG_NHWC;       // [4][9][64][64]
    int* nbr = (int*)(wpack + 147456);
    int* cnt = nbr + NIMG * 4;

    build_nbr_kernel<<<1, 256, 0, stream>>>(mask, nbr, cnt);
    pack_w_kernel<<<576, 256, 0, stream>>>(w_n0, w_x0, w_n1, w_x1, wpack);
    to_nhwc_kernel<<<1024, 256, 0, stream>>>(x, xb);

    const unsigned short* wp_n0 = wpack;
    const unsigned short* wp_x0 = wpack + 36864;
    const unsigned short* wp_n1 = wpack + 73728;
    const unsigned short* wp_x1 = wpack + 110592;

    // layer 0: xa = sum_nbr x;  h = relu(convX0(x) + convN0(xa) + b_x0 + cnt*b_n0)
    agg_kernel<<<8192, 256, 0, stream>>>(xb, xa, nbr);
    conv_fused_kernel<0><<<1024, 256, 0, stream>>>(xb, xa, wp_x0, wp_n0, b_x0, b_n0,
                                                   cnt, nullptr, hb);

    // layer 1: ha = sum_nbr h (reuse xa);  out = relu(convX1(h)+convN1(ha)+biases+x)
    agg_kernel<<<8192, 256, 0, stream>>>(hb, xa, nbr);
    conv_fused_kernel<1><<<1024, 256, 0, stream>>>(hb, xa, wp_x1, wp_n1, b_x1, b_n1,
                                                   cnt, x, d_out);
}

// Round 9
// 318.759 us; speedup vs baseline: 1.2344x; 1.2344x over previous
//
#include <hip/hip_runtime.h>

// B=4, L=64, C=64, H=W=32, K=3, CONN=4
#define NIMG 256
#define CCH 64
#define HWSZ 1024
#define IMG_NHWC 65536            // 1024 px * 64 c (bf16 elements per image)

typedef __attribute__((ext_vector_type(8))) short  s16x8;
typedef __attribute__((ext_vector_type(4))) short  s16x4;
typedef __attribute__((ext_vector_type(4))) float  f32x4;

__device__ __forceinline__ unsigned short f2bf(float f) {
    unsigned u = __builtin_bit_cast(unsigned, f);
    u += 0x7fffu + ((u >> 16) & 1u);          // RNE
    return (unsigned short)(u >> 16);
}
__device__ __forceinline__ float bf2f(unsigned short h) {
    unsigned u = ((unsigned)h) << 16;
    return __builtin_bit_cast(float, u);
}

// async global->LDS, 16B per lane. LDS dest = wave-uniform base + lane*16 (m104).
__device__ __forceinline__ void gload_lds16(const void* g, void* l) {
    __builtin_amdgcn_global_load_lds(
        (const __attribute__((address_space(1))) unsigned int*)g,
        (__attribute__((address_space(3))) unsigned int*)l, 16, 0, 0);
}

// ---------------------------------------------------------------------------
// nbr[n][4] from adjacency mask (byte-bool or int32, auto-detected). Validated R2.
// ---------------------------------------------------------------------------
__global__ __launch_bounds__(256) void build_nbr_kernel(const unsigned char* __restrict__ mraw,
                                                        int* __restrict__ nbr) {
    __shared__ int nz;
    int t = threadIdx.x;
    if (t == 0) nz = 0;
    __syncthreads();
    int local = 0;
    for (int i = t; i < 16384; i += 256) local += (mraw[i] != 0) ? 1 : 0;
    atomicAdd(&nz, local);
    __syncthreads();
    bool isByte = (nz == 1024);
    const int* mi = (const int*)mraw;
    int c = 0;
    int base = t * 64;
    for (int j = 0; j < 64; ++j) {
        int v = isByte ? (int)mraw[base + j] : mi[base + j];
        if (v != 0 && c < 4) { nbr[t * 4 + c] = j; ++c; }
    }
    for (; c < 4; ++c) nbr[t * 4 + c] = -1;
}

// ---------------------------------------------------------------------------
// Pack conv weights OIHW f32 -> [conv][tap][co][slot^(co&7)][8] bf16 (r7 layout:
// slot-XOR pre-applied so linear gload_lds staging + XOR'd ds_read are
// conflict-balanced; correctness proven r7).
// ---------------------------------------------------------------------------
__global__ __launch_bounds__(256) void pack_w_kernel(const float* __restrict__ w0,
                                                     const float* __restrict__ w1,
                                                     const float* __restrict__ w2,
                                                     const float* __restrict__ w3,
                                                     unsigned short* __restrict__ wp) {
    int idx = blockIdx.x * 256 + threadIdx.x;      // 4*9*64*64 = 147456
    if (idx >= 147456) return;
    int e  = idx & 7;
    int sp = (idx >> 3) & 7;
    int co = (idx >> 6) & 63;
    int tc = idx >> 12;                            // cv*9 + tap
    int cv = tc / 9, tap = tc - cv * 9;
    int ci = ((sp ^ (co & 7)) << 3) + e;           // logical slot stored at sp
    const float* w = (cv == 0) ? w0 : (cv == 1) ? w1 : (cv == 2) ? w2 : w3;
    wp[idx] = f2bf(w[(co * 64 + ci) * 9 + tap]);
}

// ---------------------------------------------------------------------------
// NCHW f32 -> NHWC bf16, LDS-tiled transpose. Block = quarter image (256 px).
// ---------------------------------------------------------------------------
__global__ __launch_bounds__(256) void to_nhwc_kernel(const float* __restrict__ x,
                                                      unsigned short* __restrict__ xb) {
    __shared__ unsigned short lds[256 * 68];
    int bid = blockIdx.x;                 // 1024
    int n = bid >> 2, px0 = (bid & 3) * 256;
    int t = threadIdx.x, w = t >> 6, l = t & 63;

    #pragma unroll
    for (int pp = 0; pp < 8; ++pp) {      // channel pairs per wave
        int c = w * 16 + pp * 2;
        const float* s0 = x + ((size_t)(n * 64 + c)) * HWSZ + px0;
        const float* s1 = s0 + HWSZ;
        #pragma unroll
        for (int ch = 0; ch < 4; ++ch) {
            int px = ch * 64 + l;
            unsigned pack = (unsigned)f2bf(s0[px]) | ((unsigned)f2bf(s1[px]) << 16);
            *(unsigned*)((char*)lds + px * 136 + c * 2) = pack;
        }
    }
    __syncthreads();
    #pragma unroll
    for (int it = 0; it < 8; ++it) {
        int pos = it * 256 + t;
        int px = pos >> 3, c0 = (pos & 7) * 8;
        const char* src = (const char*)lds + px * 136 + c0 * 2;
        s16x4 v0 = *(const s16x4*)src;
        s16x4 v1 = *(const s16x4*)(src + 8);
        unsigned short* dst = xb + ((size_t)(n * 1024) + px0 + px) * 64 + c0;
        *(s16x4*)dst = v0;
        *(s16x4*)(dst + 4) = v1;
    }
}

// ---------------------------------------------------------------------------
// WEIGHT-STATIONARY whole-image MFMA conv3x3 (pad 1), NHWC bf16. r9:
//  - grid 256 = 1 block/CU = 1 image; weights (all 9 taps, 72KB) staged to LDS
//    ONCE per block (was: re-staged per 8-row stripe -> 4x weight traffic).
//  - input: 4 stripes of [10 rows][34 cols][64 ci] (43.5KB), double-buffered;
//    stage s+1 issued async under compute s; one barrier per stripe.
//  - inner (tap,g) loop, XOR swizzles, A-read<->pack pairing: r7-verbatim.
//  LDS total = 73728 + 2*43520 = 160768 B (fits 160KiB).
// ---------------------------------------------------------------------------
__global__ __launch_bounds__(256, 1) void conv_mfma_kernel(const unsigned short* __restrict__ act,
                                                           const unsigned short* __restrict__ wconv,
                                                           const float* __restrict__ bias,
                                                           unsigned short* __restrict__ outp) {
    __shared__ unsigned short wlds[36864];         // 73728 B: [tap][co][sp][8]
    __shared__ unsigned short inb[2][10 * 34 * 64];// 2 x 43520 B input stripe dbuf
    int n = blockIdx.x;                            // image
    int t = threadIdx.x, w = t >> 6, l = t & 63;

    const unsigned short* img = act + ((size_t)n << 16);
    int x1 = (t >> 3) & 31, slot = t & 7;
    int c = x1 + 1;
    int sslot = slot ^ (c & 7);                    // pre-swizzled global source

    // ---- prologue: weights (18 x 4KB rounds) + stripe 0 + pad cols ----
    #pragma unroll
    for (int j = 0; j < 18; ++j) {
        int off = j * 4096 + w * 1024;             // wave-uniform byte offset
        gload_lds16((const char*)wconv + off + l * 16, (char*)wlds + off);
    }
    {
        char* ldsbase = (char*)inb[0] + (w * 8 + 1) * 128;   // wave-uniform
        #pragma unroll
        for (int r = 0; r < 10; ++r) {
            int y = -1 + r;
            if (y >= 0) {
                gload_lds16(img + (y * 32 + x1) * 64 + sslot * 8, ldsbase + r * 4352);
            } else {
                s16x8 z = {0,0,0,0,0,0,0,0};
                *(s16x8*)((char*)inb[0] + r * 4352 + c * 128 + slot * 16) = z;
            }
        }
        if (t < 160) {  // pad cols 0,33 of BOTH buffers (never overwritten)
            int r = t >> 4, cp = ((t >> 3) & 1) ? 33 : 0, sl = t & 7;
            s16x8 z = {0,0,0,0,0,0,0,0};
            int off = ((r * 34 + cp) * 128 + sl * 16) ^ ((cp & 7) << 4);
            *(s16x8*)((char*)inb[0] + off) = z;
            *(s16x8*)((char*)inb[1] + off) = z;
        }
    }
    __syncthreads();

    int lm = l & 15, kg = l >> 4;

    #pragma unroll
    for (int s = 0; s < 4; ++s) {
        // ---- stage stripe s+1 into other buffer (hidden under compute) ----
        if (s < 3) {
            int y0n = (s + 1) * 8;
            char* ldsbase = (char*)inb[(s + 1) & 1] + (w * 8 + 1) * 128;
            #pragma unroll
            for (int r = 0; r < 10; ++r) {
                int y = y0n - 1 + r;
                if (y < 32) {
                    gload_lds16(img + (y * 32 + x1) * 64 + sslot * 8, ldsbase + r * 4352);
                } else {
                    s16x8 z = {0,0,0,0,0,0,0,0};
                    *(s16x8*)((char*)inb[(s + 1) & 1] + r * 4352 + c * 128 + slot * 16) = z;
                }
            }
        }

        // ---- compute stripe s ----
        const char* tile = (const char*)inb[s & 1];
        f32x4 acc[4][4];
        #pragma unroll
        for (int m = 0; m < 4; ++m)
            #pragma unroll
            for (int p = 0; p < 4; ++p) acc[m][p] = (f32x4){0.f, 0.f, 0.f, 0.f};

        #pragma unroll
        for (int tap = 0; tap < 9; ++tap) {
            const int dy = tap / 3, dx = tap % 3;
            #pragma unroll
            for (int g = 0; g < 2; ++g) {
                s16x8 a[4], bfr[4];
                #pragma unroll
                for (int m = 0; m < 4; ++m) {
                    int row = m * 16 + lm;
                    int ao  = tap * 8192 + row * 128 + (((g * 4 + kg) ^ (lm & 7)) * 16);
                    a[m] = *(const s16x8*)((const char*)wlds + ao);
                }
                #pragma unroll
                for (int p = 0; p < 4; ++p) {
                    int r  = 2 * w + (p >> 1) + dy;
                    int xl = (p & 1) * 16 + lm + dx;
                    int lb = (r * 4352 + xl * 128 + g * 64 + kg * 16) ^ ((xl & 7) << 4);
                    bfr[p] = *(const s16x8*)(tile + lb);
                }
                #pragma unroll
                for (int m = 0; m < 4; ++m)
                    #pragma unroll
                    for (int p = 0; p < 4; ++p)
                        acc[m][p] = __builtin_amdgcn_mfma_f32_16x16x32_bf16(a[m], bfr[p], acc[m][p], 0, 0, 0);
            }
        }

        // ---- epilogue for stripe s. D: col(px)=lane&15, row(co)=kg*4+reg ----
        int y0 = s * 8;
        #pragma unroll
        for (int m = 0; m < 4; ++m) {
            f32x4 bv = *(const f32x4*)(bias + m * 16 + kg * 4);
            #pragma unroll
            for (int p = 0; p < 4; ++p) {
                int y  = y0 + 2 * w + (p >> 1);
                int xx = (p & 1) * 16 + lm;
                s16x4 o;
                #pragma unroll
                for (int j = 0; j < 4; ++j) o[j] = (short)f2bf(acc[m][p][j] + bv[j]);
                *(s16x4*)(outp + (((size_t)n * 1024 + y * 32 + xx) * 64) + m * 16 + kg * 4) = o;
            }
        }
        if (s < 3) __syncthreads();   // drain stage(s+1); all waves done with buf
    }
}

// ---------------------------------------------------------------------------
// h = relu(hx + sum_k nset[nbr_k])  in-place on NHWC bf16 (16B per thread).
// ---------------------------------------------------------------------------
__global__ __launch_bounds__(256) void agg_relu_kernel(unsigned short* __restrict__ hx,
                                                       const unsigned short* __restrict__ nset,
                                                       const int* __restrict__ nbr) {
    int bid = blockIdx.x;                          // 8192
    int n = bid >> 5;                              // uniform per block
    int b = n >> 6;
    int rem = ((bid & 31) << 8) + threadIdx.x;     // 16B unit within image
    size_t u = (((size_t)n) << 13) + rem;
    s16x8 hv = *(const s16x8*)(hx + u * 8);
    float s[8];
    #pragma unroll
    for (int j = 0; j < 8; ++j) s[j] = bf2f((unsigned short)hv[j]);
    #pragma unroll
    for (int k = 0; k < 4; ++k) {
        int jn = nbr[n * 4 + k];
        if (jn >= 0) {
            s16x8 nv = *(const s16x8*)(nset + ((((size_t)(b * 64 + jn)) << 13) + rem) * 8);
            #pragma unroll
            for (int j = 0; j < 8; ++j) s[j] += bf2f((unsigned short)nv[j]);
        }
    }
    s16x8 o;
    #pragma unroll
    for (int j = 0; j < 8; ++j) o[j] = (short)f2bf(fmaxf(s[j], 0.f));
    *(s16x8*)(hx + u * 8) = o;
}

// ---------------------------------------------------------------------------
// out = relu(h2x + sum_k nset[nbr_k] + x), NHWC bf16 -> NCHW f32 via LDS.
// ---------------------------------------------------------------------------
__global__ __launch_bounds__(256) void final_kernel(const unsigned short* __restrict__ h2x,
                                                    const unsigned short* __restrict__ nset,
                                                    const int* __restrict__ nbr,
                                                    const float* __restrict__ x,
                                                    float* __restrict__ out) {
    __shared__ float lds[128 * 68];
    int bid = blockIdx.x;                          // 2048
    int n = bid >> 3, px0 = (bid & 7) * 128;
    int b = n >> 6;
    int t = threadIdx.x;
    int j0 = nbr[n * 4 + 0], j1 = nbr[n * 4 + 1], j2 = nbr[n * 4 + 2], j3 = nbr[n * 4 + 3];
    size_t base = ((size_t)n * 1024 + px0) * 64;
    size_t nb[4];
    nb[0] = ((size_t)(b * 64 + (j0 < 0 ? 0 : j0)) * 1024 + px0) * 64;
    nb[1] = ((size_t)(b * 64 + (j1 < 0 ? 0 : j1)) * 1024 + px0) * 64;
    nb[2] = ((size_t)(b * 64 + (j2 < 0 ? 0 : j2)) * 1024 + px0) * 64;
    nb[3] = ((size_t)(b * 64 + (j3 < 0 ? 0 : j3)) * 1024 + px0) * 64;
    int use[4] = {j0 >= 0, j1 >= 0, j2 >= 0, j3 >= 0};

    #pragma unroll
    for (int it = 0; it < 4; ++it) {
        int pos = it * 256 + t;
        int px = pos >> 3, c0 = (pos & 7) * 8;
        int off = px * 64 + c0;
        float s[8];
        s16x8 hv = *(const s16x8*)(h2x + base + off);
        #pragma unroll
        for (int j = 0; j < 8; ++j) s[j] = bf2f((unsigned short)hv[j]);
        #pragma unroll
        for (int k = 0; k < 4; ++k) {
            if (use[k]) {
                s16x8 nv = *(const s16x8*)(nset + nb[k] + off);
                #pragma unroll
                for (int j = 0; j < 8; ++j) s[j] += bf2f((unsigned short)nv[j]);
            }
        }
        float* dst = &lds[px * 68 + c0];
        *(f32x4*)dst = (f32x4){s[0], s[1], s[2], s[3]};
        *(f32x4*)(dst + 4) = (f32x4){s[4], s[5], s[6], s[7]};
    }
    __syncthreads();

    int w = t >> 6, l = t & 63;
    #pragma unroll
    for (int q = 0; q < 4; ++q) {
        int c0 = w * 16 + q * 4;
        #pragma unroll
        for (int half = 0; half < 2; ++half) {
            int px = half * 64 + l;
            f32x4 v = *(const f32x4*)&lds[px * 68 + c0];
            #pragma unroll
            for (int j = 0; j < 4; ++j) {
                size_t a = ((size_t)(n * 64) + c0 + j) * HWSZ + px0 + px;
                out[a] = fmaxf(v[j] + x[a], 0.f);
            }
        }
    }
}

// ---------------------------------------------------------------------------
extern "C" void kernel_launch(void* const* d_in, const int* in_sizes, int n_in,
                              void* d_out, int out_size, void* d_ws, size_t ws_size,
                              hipStream_t stream) {
    const float* x    = (const float*)d_in[0];
    const float* w_x0 = (const float*)d_in[1];
    const float* b_x0 = (const float*)d_in[2];
    const float* w_n0 = (const float*)d_in[3];
    const float* b_n0 = (const float*)d_in[4];
    const float* w_x1 = (const float*)d_in[5];
    const float* b_x1 = (const float*)d_in[6];
    const float* w_n1 = (const float*)d_in[7];
    const float* b_n1 = (const float*)d_in[8];
    const unsigned char* mask = (const unsigned char*)d_in[9];

    unsigned short* xb    = (unsigned short*)d_ws;              // x NHWC bf16 -> later h2x
    unsigned short* hxb   = xb  + (size_t)NIMG * IMG_NHWC;      // hx -> h (in-place agg)
    unsigned short* nsetb = hxb + (size_t)NIMG * IMG_NHWC;      // n_set
    unsigned short* wpack = nsetb + (size_t)NIMG * IMG_NHWC;    // [4][9][64][64]
    int* nbr = (int*)(wpack + 147456);

    build_nbr_kernel<<<1, 256, 0, stream>>>(mask, nbr);
    pack_w_kernel<<<576, 256, 0, stream>>>(w_n0, w_x0, w_n1, w_x1, wpack);
    to_nhwc_kernel<<<1024, 256, 0, stream>>>(x, xb);

    const unsigned short* wp_n0 = wpack;
    const unsigned short* wp_x0 = wpack + 36864;
    const unsigned short* wp_n1 = wpack + 73728;
    const unsigned short* wp_x1 = wpack + 110592;

    // layer 0
    conv_mfma_kernel<<<256, 256, 0, stream>>>(xb, wp_n0, b_n0, nsetb);
    conv_mfma_kernel<<<256, 256, 0, stream>>>(xb, wp_x0, b_x0, hxb);
    agg_relu_kernel<<<8192, 256, 0, stream>>>(hxb, nsetb, nbr);       // hxb -> h

    // layer 1 (h2x overwrites xb)
    conv_mfma_kernel<<<256, 256, 0, stream>>>(hxb, wp_n1, b_n1, nsetb);
    conv_mfma_kernel<<<256, 256, 0, stream>>>(hxb, wp_x1, b_x1, xb);
    final_kernel<<<2048, 256, 0, stream>>>(xb, nsetb, nbr, x, (float*)d_out);
}